// Round 1
// baseline (3475.489 us; speedup 1.0000x reference)
//
#include <hip/hip_runtime.h>

#define NPTS 40000
#define NEDGE 1000000
#define BN_EPS 1e-5f

// ---------------------------------------------------------------------------
// Edge precompute: window weight + bilinear corner weights + base cell index.
// eidx[e] = recv*16 + ix*4 + iy  (or -1 if window weight == 0)
// ew[e]   = (w00, w01, w10, w11) each premultiplied by win
// corner cell offsets (in cells): +0, +1, +4, +5
// ---------------------------------------------------------------------------
__global__ void edge_pre_kernel(const float* __restrict__ rel_pos,
                                const int* __restrict__ receivers,
                                const int* __restrict__ ws_ptr,
                                int* __restrict__ eidx,
                                float4* __restrict__ ew) {
    int e = blockIdx.x * blockDim.x + threadIdx.x;
    if (e >= NEDGE) return;
    float ws = (float)ws_ptr[0];
    float inv_ws = 1.0f / ws;
    float ux = rel_pos[2 * e] * inv_ws;
    float uy = rel_pos[2 * e + 1] * inv_ws;
    float q = 1.0f - (ux * ux + uy * uy);
    float win = (q > 0.0f) ? q * q * q : 0.0f;
    if (!(win > 0.0f)) {
        eidx[e] = -1;
        ew[e] = make_float4(0.f, 0.f, 0.f, 0.f);
        return;
    }
    // grid = clip((u+1)*0.5*(K-1), 0, K-1), K=4
    float gx = fminf(fmaxf((ux + 1.0f) * 1.5f, 0.0f), 3.0f);
    float gy = fminf(fmaxf((uy + 1.0f) * 1.5f, 0.0f), 3.0f);
    int ix = (int)floorf(gx); ix = ix < 0 ? 0 : (ix > 2 ? 2 : ix);
    int iy = (int)floorf(gy); iy = iy < 0 ? 0 : (iy > 2 ? 2 : iy);
    float fx = gx - (float)ix;
    float fy = gy - (float)iy;
    int recv = receivers[e];
    eidx[e] = recv * 16 + ix * 4 + iy;
    ew[e] = make_float4((1.f - fx) * (1.f - fy) * win,
                        (1.f - fx) * fy * win,
                        fx * (1.f - fy) * win,
                        fx * fy * win);
}

// xa = concat([x, y], axis=-1)  -> [N, 64]
__global__ void build_xa_kernel(const float* __restrict__ x,
                                const float* __restrict__ y,
                                float* __restrict__ xa) {
    int t = blockIdx.x * blockDim.x + threadIdx.x;
    if (t >= NPTS * 64) return;
    int n = t >> 6, c = t & 63;
    xa[t] = (c < 32) ? x[n * 32 + c] : y[n * 32 + (c - 32)];
}

// ---------------------------------------------------------------------------
// Scatter: one thread per (edge, channel). 4 atomic adds into S[N*16, CIN].
// ---------------------------------------------------------------------------
template <int CIN>
__global__ void scatter_kernel(const float* __restrict__ feat,
                               const int* __restrict__ senders,
                               const int* __restrict__ eidx,
                               const float4* __restrict__ ew,
                               float* __restrict__ S) {
    int t = blockIdx.x * blockDim.x + threadIdx.x;
    if (t >= NEDGE * CIN) return;
    int e = t / CIN;
    int c = t % CIN;
    int idx = eidx[e];
    if (idx < 0) return;
    float f = feat[(size_t)senders[e] * CIN + c];
    float4 w = ew[e];
    float* base = S + (size_t)idx * CIN + c;
    atomicAdd(base, w.x * f);
    atomicAdd(base + CIN, w.y * f);
    atomicAdd(base + 4 * CIN, w.z * f);
    atomicAdd(base + 5 * CIN, w.w * f);
}

// ---------------------------------------------------------------------------
// GEMM: P[n][d] = a[n] * sum_m S[n][m] * W[m][d],  m < 16*CIN
// block = 256 threads = (COUT cols) x (R rows); LDS-staged S chunks.
// ---------------------------------------------------------------------------
template <int CIN, int COUT>
__global__ __launch_bounds__(256) void gemm_kernel(const float* __restrict__ S,
                                                   const float* __restrict__ W,
                                                   const float* __restrict__ a,
                                                   float* __restrict__ P) {
    constexpr int M = 16 * CIN;
    constexpr int R = 256 / COUT;
    __shared__ float sS[R][128];
    int tid = threadIdx.x;
    int d = tid % COUT;
    int r = tid / COUT;
    int n0 = blockIdx.x * R;
    float acc = 0.0f;
    for (int m0 = 0; m0 < M; m0 += 128) {
        for (int i = tid; i < R * 128; i += 256) {
            int rr = i >> 7, mm = i & 127;
            sS[rr][mm] = S[(size_t)(n0 + rr) * M + m0 + mm];
        }
        __syncthreads();
#pragma unroll 8
        for (int mm = 0; mm < 128; ++mm) {
            acc = fmaf(sS[r][mm], W[(size_t)(m0 + mm) * COUT + d], acc);
        }
        __syncthreads();
    }
    P[(size_t)(n0 + r) * COUT + d] = a[n0 + r] * acc;
}

// BN stats: st[0..COUT) = sum, st[COUT..2*COUT) = sumsq (st pre-zeroed)
template <int COUT>
__global__ void stats_kernel(const float* __restrict__ P, float* __restrict__ st) {
    int d = threadIdx.x;
    float s = 0.f, s2 = 0.f;
    for (int n = blockIdx.x; n < NPTS; n += gridDim.x) {
        float v = P[(size_t)n * COUT + d];
        s += v;
        s2 += v * v;
    }
    atomicAdd(&st[d], s);
    atomicAdd(&st[COUT + d], s2);
}

// sc[d] = invstd*g, sc[COUT+d] = b - mean*invstd*g
template <int COUT>
__global__ void finalize_bn_kernel(const float* __restrict__ st,
                                   const float* __restrict__ g,
                                   const float* __restrict__ b,
                                   float* __restrict__ sc) {
    int d = threadIdx.x;
    float mean = st[d] / (float)NPTS;
    float var = st[COUT + d] / (float)NPTS - mean * mean;
    float inv = rsqrtf(var + BN_EPS);
    float scale = inv * g[d];
    sc[d] = scale;
    sc[COUT + d] = b[d] - mean * scale;
}

template <int COUT>
__global__ void apply_relu_kernel(float* __restrict__ P, const float* __restrict__ sc) {
    int t = blockIdx.x * blockDim.x + threadIdx.x;
    if (t >= NPTS * COUT) return;
    int d = t % COUT;
    float v = P[t] * sc[d] + sc[COUT + d];
    P[t] = fmaxf(v, 0.0f);
}

// out = 2*x*sigmoid(v) + 2*y*(1-sigmoid(v)),  v = P*scale + shift, COUT=32
__global__ void apply_sigmix_kernel(const float* __restrict__ P,
                                    const float* __restrict__ sc,
                                    const float* __restrict__ x,
                                    const float* __restrict__ y,
                                    float* __restrict__ out) {
    int t = blockIdx.x * blockDim.x + threadIdx.x;
    if (t >= NPTS * 32) return;
    int d = t & 31;
    float v = P[t] * sc[d] + sc[32 + d];
    float w = 1.0f / (1.0f + expf(-v));
    out[t] = 2.0f * x[t] * w + 2.0f * y[t] * (1.0f - w);
}

// ---------------------------------------------------------------------------
// One cconv layer: zero S, scatter, GEMM(+a), BN stats + finalize.
// ---------------------------------------------------------------------------
template <int CIN, int COUT>
static void run_cconv(const float* feat, const float* W, const float* g, const float* b,
                      const float* a, const int* senders, const int* eidx, const float4* ew,
                      float* S, float* st, float* sc, float* P, hipStream_t stream) {
    hipMemsetAsync(S, 0, (size_t)NPTS * 16 * CIN * sizeof(float), stream);
    int nthr = NEDGE * CIN;
    scatter_kernel<CIN><<<(nthr + 255) / 256, 256, 0, stream>>>(feat, senders, eidx, ew, S);
    constexpr int R = 256 / COUT;
    gemm_kernel<CIN, COUT><<<NPTS / R, 256, 0, stream>>>(S, W, a, P);
    hipMemsetAsync(st, 0, 2 * COUT * sizeof(float), stream);
    stats_kernel<COUT><<<128, COUT, 0, stream>>>(P, st);
    finalize_bn_kernel<COUT><<<1, COUT, 0, stream>>>(st, g, b, sc);
}

extern "C" void kernel_launch(void* const* d_in, const int* in_sizes, int n_in,
                              void* d_out, int out_size, void* d_ws, size_t ws_size,
                              hipStream_t stream) {
    const float* x = (const float*)d_in[0];
    const float* y = (const float*)d_in[1];
    const int* senders = (const int*)d_in[2];
    const int* receivers = (const int*)d_in[3];
    const float* rel_pos = (const float*)d_in[4];
    const int* ws_ptr = (const int*)d_in[5];
    const float* a = (const float*)d_in[6];
    const float* W1 = (const float*)d_in[7];
    const float* W2 = (const float*)d_in[8];
    const float* W3 = (const float*)d_in[9];
    const float* W4 = (const float*)d_in[10];
    const float* g1 = (const float*)d_in[11];
    const float* b1 = (const float*)d_in[12];
    const float* g2 = (const float*)d_in[13];
    const float* b2 = (const float*)d_in[14];
    const float* g3 = (const float*)d_in[15];
    const float* b3 = (const float*)d_in[16];
    const float* g4 = (const float*)d_in[17];
    const float* b4 = (const float*)d_in[18];

    char* ws = (char*)d_ws;
    size_t off = 0;
    auto alloc = [&](size_t bytes) -> void* {
        void* p = ws + off;
        off += (bytes + 255) & ~(size_t)255;
        return p;
    };
    int* eidx = (int*)alloc((size_t)NEDGE * sizeof(int));
    float4* ew = (float4*)alloc((size_t)NEDGE * sizeof(float4));
    float* S = (float*)alloc((size_t)NPTS * 16 * 64 * sizeof(float));
    float* xa = (float*)alloc((size_t)NPTS * 64 * sizeof(float));  // also P3/xl2
    float* P1 = (float*)alloc((size_t)NPTS * 64 * sizeof(float));
    float* P2 = (float*)alloc((size_t)NPTS * 32 * sizeof(float));  // also P4
    float* xo = (float*)alloc((size_t)NPTS * 32 * sizeof(float));
    float* st = (float*)alloc(2 * 64 * sizeof(float));
    float* sc = (float*)alloc(2 * 64 * sizeof(float));
    (void)ws_size; (void)in_sizes; (void)n_in; (void)out_size;

    // Edge precompute + input concat
    edge_pre_kernel<<<(NEDGE + 255) / 256, 256, 0, stream>>>(rel_pos, receivers, ws_ptr, eidx, ew);
    build_xa_kernel<<<(NPTS * 64 + 255) / 256, 256, 0, stream>>>(x, y, xa);

    // Layer 1: cconv(xa; W1) -> P1, relu(bn) in place
    run_cconv<64, 64>(xa, W1, g1, b1, a, senders, eidx, ew, S, st, sc, P1, stream);
    apply_relu_kernel<64><<<(NPTS * 64 + 255) / 256, 256, 0, stream>>>(P1, sc);

    // Layer 2: cconv(P1; W2) -> P2, sigmoid-mix -> xo
    run_cconv<64, 32>(P1, W2, g2, b2, a, senders, eidx, ew, S, st, sc, P2, stream);
    apply_sigmix_kernel<<<(NPTS * 32 + 255) / 256, 256, 0, stream>>>(P2, sc, x, y, xo);

    // Layer 3: cconv(xo; W3) -> xa (reused as P3), relu(bn) in place
    run_cconv<32, 64>(xo, W3, g3, b3, a, senders, eidx, ew, S, st, sc, xa, stream);
    apply_relu_kernel<64><<<(NPTS * 64 + 255) / 256, 256, 0, stream>>>(xa, sc);

    // Layer 4: cconv(xa; W4) -> P2 (reused as P4), sigmoid-mix -> out
    run_cconv<64, 32>(xa, W4, g4, b4, a, senders, eidx, ew, S, st, sc, P2, stream);
    apply_sigmix_kernel<<<(NPTS * 32 + 255) / 256, 256, 0, stream>>>(P2, sc, x, y, (float*)d_out);
}

// Round 2
// 1668.093 us; speedup vs baseline: 2.0835x; 2.0835x over previous
//
#include <hip/hip_runtime.h>

#define NPTS 40000
#define NEDGE 1000000
#define BN_EPS 1e-5f

// ===========================================================================
// CSR build: edges sorted by receiver, invalid (win==0) edges dropped.
// Record per edge: sc = (sender, cell)  ew4 = win-premultiplied corner weights
// corners in m-space: cell, cell+1, cell+4, cell+5 (each * CIN)
// ===========================================================================

__device__ inline bool edge_geom(const float* rel_pos, const int* ws_ptr, int e,
                                 int& cell, float4& w4) {
    float ws = (float)ws_ptr[0];
    float inv_ws = 1.0f / ws;
    float ux = rel_pos[2 * e] * inv_ws;
    float uy = rel_pos[2 * e + 1] * inv_ws;
    float q = 1.0f - (ux * ux + uy * uy);
    if (!(q > 0.0f)) return false;
    float win = q * q * q;
    float gx = fminf(fmaxf((ux + 1.0f) * 1.5f, 0.0f), 3.0f);
    float gy = fminf(fmaxf((uy + 1.0f) * 1.5f, 0.0f), 3.0f);
    int ix = (int)floorf(gx); ix = ix < 0 ? 0 : (ix > 2 ? 2 : ix);
    int iy = (int)floorf(gy); iy = iy < 0 ? 0 : (iy > 2 ? 2 : iy);
    float fx = gx - (float)ix;
    float fy = gy - (float)iy;
    cell = ix * 4 + iy;
    w4 = make_float4((1.f - fx) * (1.f - fy) * win,
                     (1.f - fx) * fy * win,
                     fx * (1.f - fy) * win,
                     fx * fy * win);
    return true;
}

__global__ void hist_kernel(const float* __restrict__ rel_pos,
                            const int* __restrict__ receivers,
                            const int* __restrict__ ws_ptr,
                            int* __restrict__ cnt) {
    int e = blockIdx.x * blockDim.x + threadIdx.x;
    if (e >= NEDGE) return;
    int cell; float4 w4;
    if (edge_geom(rel_pos, ws_ptr, e, cell, w4))
        atomicAdd(&cnt[receivers[e]], 1);
}

// one block, 1024 threads: exclusive scan of 40000 counts -> rowptr[40001]
__global__ __launch_bounds__(1024) void scan_kernel(const int* __restrict__ cnt,
                                                    int* __restrict__ rowptr) {
    __shared__ int part[1024];
    int t = threadIdx.x;
    const int CHUNK = 40;  // 1000 threads * 40 = 40000
    int base = t * CHUNK;
    int s = 0;
    if (t < 1000)
        for (int i = 0; i < CHUNK; ++i) s += cnt[base + i];
    part[t] = s;
    __syncthreads();
    for (int off = 1; off < 1024; off <<= 1) {
        int v = (t >= off) ? part[t - off] : 0;
        __syncthreads();
        part[t] += v;
        __syncthreads();
    }
    int excl = (t == 0) ? 0 : part[t - 1];
    if (t < 1000) {
        int run = excl;
        for (int i = 0; i < CHUNK; ++i) { rowptr[base + i] = run; run += cnt[base + i]; }
        if (t == 999) rowptr[NPTS] = run;
    }
}

__global__ void fill_kernel(const float* __restrict__ rel_pos,
                            const int* __restrict__ receivers,
                            const int* __restrict__ senders,
                            const int* __restrict__ ws_ptr,
                            const int* __restrict__ rowptr,
                            int* __restrict__ cursor,
                            int2* __restrict__ sc,
                            float4* __restrict__ ew4) {
    int e = blockIdx.x * blockDim.x + threadIdx.x;
    if (e >= NEDGE) return;
    int cell; float4 w4;
    if (!edge_geom(rel_pos, ws_ptr, e, cell, w4)) return;
    int recv = receivers[e];
    int pos = rowptr[recv] + atomicAdd(&cursor[recv], 1);
    sc[pos] = make_int2(senders[e], cell);
    ew4[pos] = w4;
}

// xa = concat([x, y], axis=-1)  -> [N, 64]
__global__ void build_xa_kernel(const float* __restrict__ x,
                                const float* __restrict__ y,
                                float* __restrict__ xa) {
    int t = blockIdx.x * blockDim.x + threadIdx.x;
    if (t >= NPTS * 64) return;
    int n = t >> 6, c = t & 63;
    xa[t] = (c < 32) ? x[n * 32 + c] : y[n * 32 + (c - 32)];
}

// ===========================================================================
// Fused cconv layer: per block 16 receivers. Phase 1: edge accumulation into
// LDS S rows (slot-owned -> no atomics). Phase 2: GEMM vs W + scale by a.
// ===========================================================================
template <int CIN, int COUT>
__global__ __launch_bounds__(256) void fused_layer(const float* __restrict__ feat,
                                                   const int2* __restrict__ sc,
                                                   const float4* __restrict__ ew4,
                                                   const int* __restrict__ rowptr,
                                                   const float* __restrict__ W,
                                                   const float* __restrict__ a,
                                                   float* __restrict__ P) {
    constexpr int RB = 16;            // receivers per block
    constexpr int M = 16 * CIN;       // GEMM K dimension
    constexpr int LDM = M + 4;        // padded row stride (bank de-conflict)
    constexpr int VEC = CIN / 16;     // channels per lane in phase 1 (4 or 2)
    __shared__ float S[RB * LDM];

    int tid = threadIdx.x;
    // --- zero LDS ---
    for (int i = tid * 4; i < RB * LDM; i += 256 * 4) {
        S[i] = 0.f; S[i + 1] = 0.f; S[i + 2] = 0.f; S[i + 3] = 0.f;
    }
    __syncthreads();

    // --- phase 1: accumulate edges ---
    int lane = tid & 63;
    int wave = tid >> 6;
    int slot = lane >> 4;             // 4 slots per wave
    int q = lane & 15;                // 16 lanes per slot
    int rloc = wave * 4 + slot;       // 0..15
    int rglob = blockIdx.x * RB + rloc;
    int rs = rowptr[rglob];
    int deg = rowptr[rglob + 1] - rs;
    int md = deg;
    md = max(md, __shfl_xor(md, 16));
    md = max(md, __shfl_xor(md, 32));

    float* srow = &S[rloc * LDM];
    for (int k = 0; k < md; ++k) {
        bool act = k < deg;
        int e = act ? rs + k : rs;
        int2 rec = sc[e];
        float4 w = ew4[e];
        if (!act) { w.x = 0.f; w.y = 0.f; w.z = 0.f; w.w = 0.f; }
        const float* fp = feat + (size_t)rec.x * CIN + q * VEC;
        float f[VEC];
        if constexpr (VEC == 4) {
            float4 fv = *(const float4*)fp;
            f[0] = fv.x; f[1] = fv.y; f[2] = fv.z; f[3] = fv.w;
        } else {
            float2 fv = *(const float2*)fp;
            f[0] = fv.x; f[1] = fv.y;
        }
        int cb = rec.y * CIN + q * VEC;
        float wc[4] = {w.x, w.y, w.z, w.w};
        const int coff[4] = {0, CIN, 4 * CIN, 5 * CIN};
#pragma unroll
        for (int c = 0; c < 4; ++c) {
            float* p = srow + cb + coff[c];
            if constexpr (VEC == 4) {
                float4 old = *(float4*)p;
                old.x = fmaf(wc[c], f[0], old.x);
                old.y = fmaf(wc[c], f[1], old.y);
                old.z = fmaf(wc[c], f[2], old.z);
                old.w = fmaf(wc[c], f[3], old.w);
                *(float4*)p = old;
            } else {
                float2 old = *(float2*)p;
                old.x = fmaf(wc[c], f[0], old.x);
                old.y = fmaf(wc[c], f[1], old.y);
                *(float2*)p = old;
            }
        }
    }
    __syncthreads();

    // --- phase 2: GEMM  P[n][d] = a[n] * sum_m S[n][m] * W[m][d] ---
    constexpr int DVEC = COUT / 16;   // 4 or 2 outputs per thread
    int dq = tid & 15;                // 16 d-quads cover COUT
    int rg = tid >> 4;                // 16 rows
    const float* sr = &S[rg * LDM];
    float acc[DVEC];
#pragma unroll
    for (int t = 0; t < DVEC; ++t) acc[t] = 0.f;

    for (int m = 0; m < M; m += 4) {
        float4 s4 = *(const float4*)&sr[m];
        const float* wp = W + (size_t)m * COUT + dq * DVEC;
#pragma unroll
        for (int j = 0; j < 4; ++j) {
            float sv = (&s4.x)[j];
            if constexpr (DVEC == 4) {
                float4 wv = *(const float4*)(wp + j * COUT);
                acc[0] = fmaf(sv, wv.x, acc[0]);
                acc[1] = fmaf(sv, wv.y, acc[1]);
                acc[2] = fmaf(sv, wv.z, acc[2]);
                acc[3] = fmaf(sv, wv.w, acc[3]);
            } else {
                float2 wv = *(const float2*)(wp + j * COUT);
                acc[0] = fmaf(sv, wv.x, acc[0]);
                acc[1] = fmaf(sv, wv.y, acc[1]);
            }
        }
    }
    int n = blockIdx.x * RB + rg;
    float av = a[n];
#pragma unroll
    for (int t = 0; t < DVEC; ++t)
        P[(size_t)n * COUT + dq * DVEC + t] = av * acc[t];
}

// ===========================================================================
// BatchNorm pieces
// ===========================================================================
template <int COUT>
__global__ void stats_kernel(const float* __restrict__ P, float* __restrict__ st) {
    int d = threadIdx.x;
    float s = 0.f, s2 = 0.f;
    for (int n = blockIdx.x; n < NPTS; n += gridDim.x) {
        float v = P[(size_t)n * COUT + d];
        s += v;
        s2 += v * v;
    }
    atomicAdd(&st[d], s);
    atomicAdd(&st[COUT + d], s2);
}

template <int COUT>
__global__ void finalize_bn_kernel(const float* __restrict__ st,
                                   const float* __restrict__ g,
                                   const float* __restrict__ b,
                                   float* __restrict__ scb) {
    int d = threadIdx.x;
    float mean = st[d] / (float)NPTS;
    float var = st[COUT + d] / (float)NPTS - mean * mean;
    float inv = rsqrtf(var + BN_EPS);
    float scale = inv * g[d];
    scb[d] = scale;
    scb[COUT + d] = b[d] - mean * scale;
}

template <int COUT>
__global__ void apply_relu_kernel(float* __restrict__ P, const float* __restrict__ scb) {
    int t = blockIdx.x * blockDim.x + threadIdx.x;
    if (t >= NPTS * COUT) return;
    int d = t % COUT;
    float v = P[t] * scb[d] + scb[COUT + d];
    P[t] = fmaxf(v, 0.0f);
}

__global__ void apply_sigmix_kernel(const float* __restrict__ P,
                                    const float* __restrict__ scb,
                                    const float* __restrict__ x,
                                    const float* __restrict__ y,
                                    float* __restrict__ out) {
    int t = blockIdx.x * blockDim.x + threadIdx.x;
    if (t >= NPTS * 32) return;
    int d = t & 31;
    float v = P[t] * scb[d] + scb[32 + d];
    float w = 1.0f / (1.0f + expf(-v));
    out[t] = 2.0f * x[t] * w + 2.0f * y[t] * (1.0f - w);
}

// ===========================================================================
template <int CIN, int COUT>
static void run_layer(const float* feat, const int2* sc, const float4* ew4,
                      const int* rowptr, const float* W, const float* g,
                      const float* b, const float* a, float* st, float* scb,
                      float* P, hipStream_t stream) {
    fused_layer<CIN, COUT><<<NPTS / 16, 256, 0, stream>>>(feat, sc, ew4, rowptr, W, a, P);
    hipMemsetAsync(st, 0, 2 * COUT * sizeof(float), stream);
    stats_kernel<COUT><<<128, COUT, 0, stream>>>(P, st);
    finalize_bn_kernel<COUT><<<1, COUT, 0, stream>>>(st, g, b, scb);
}

extern "C" void kernel_launch(void* const* d_in, const int* in_sizes, int n_in,
                              void* d_out, int out_size, void* d_ws, size_t ws_size,
                              hipStream_t stream) {
    const float* x = (const float*)d_in[0];
    const float* y = (const float*)d_in[1];
    const int* senders = (const int*)d_in[2];
    const int* receivers = (const int*)d_in[3];
    const float* rel_pos = (const float*)d_in[4];
    const int* ws_ptr = (const int*)d_in[5];
    const float* a = (const float*)d_in[6];
    const float* W1 = (const float*)d_in[7];
    const float* W2 = (const float*)d_in[8];
    const float* W3 = (const float*)d_in[9];
    const float* W4 = (const float*)d_in[10];
    const float* g1 = (const float*)d_in[11];
    const float* b1 = (const float*)d_in[12];
    const float* g2 = (const float*)d_in[13];
    const float* b2 = (const float*)d_in[14];
    const float* g3 = (const float*)d_in[15];
    const float* b3 = (const float*)d_in[16];
    const float* g4 = (const float*)d_in[17];
    const float* b4 = (const float*)d_in[18];

    char* ws = (char*)d_ws;
    size_t off = 0;
    auto alloc = [&](size_t bytes) -> void* {
        void* p = ws + off;
        off += (bytes + 255) & ~(size_t)255;
        return p;
    };
    int* cnt = (int*)alloc((size_t)NPTS * sizeof(int));
    int* rowptr = (int*)alloc((size_t)(NPTS + 1) * sizeof(int));
    int* cursor = (int*)alloc((size_t)NPTS * sizeof(int));
    int2* sc = (int2*)alloc((size_t)(NEDGE + 4) * sizeof(int2));
    float4* ew4 = (float4*)alloc((size_t)(NEDGE + 4) * sizeof(float4));
    float* xa = (float*)alloc((size_t)NPTS * 64 * sizeof(float));  // also P3
    float* P1 = (float*)alloc((size_t)NPTS * 64 * sizeof(float));
    float* P2 = (float*)alloc((size_t)NPTS * 32 * sizeof(float));  // also P4
    float* xo = (float*)alloc((size_t)NPTS * 32 * sizeof(float));
    float* st = (float*)alloc(2 * 64 * sizeof(float));
    float* scb = (float*)alloc(2 * 64 * sizeof(float));
    (void)ws_size; (void)in_sizes; (void)n_in; (void)out_size;

    // --- CSR build (shared by all 4 layers) ---
    hipMemsetAsync(cnt, 0, (size_t)NPTS * sizeof(int), stream);
    hist_kernel<<<(NEDGE + 255) / 256, 256, 0, stream>>>(rel_pos, receivers, ws_ptr, cnt);
    scan_kernel<<<1, 1024, 0, stream>>>(cnt, rowptr);
    hipMemsetAsync(cursor, 0, (size_t)NPTS * sizeof(int), stream);
    fill_kernel<<<(NEDGE + 255) / 256, 256, 0, stream>>>(rel_pos, receivers, senders, ws_ptr,
                                                         rowptr, cursor, sc, ew4);
    build_xa_kernel<<<(NPTS * 64 + 255) / 256, 256, 0, stream>>>(x, y, xa);

    // Layer 1: cconv(xa; W1) -> P1, relu(bn) in place
    run_layer<64, 64>(xa, sc, ew4, rowptr, W1, g1, b1, a, st, scb, P1, stream);
    apply_relu_kernel<64><<<(NPTS * 64 + 255) / 256, 256, 0, stream>>>(P1, scb);

    // Layer 2: cconv(P1; W2) -> P2, sigmoid-mix -> xo
    run_layer<64, 32>(P1, sc, ew4, rowptr, W2, g2, b2, a, st, scb, P2, stream);
    apply_sigmix_kernel<<<(NPTS * 32 + 255) / 256, 256, 0, stream>>>(P2, scb, x, y, xo);

    // Layer 3: cconv(xo; W3) -> xa (reuse), relu(bn) in place
    run_layer<32, 64>(xo, sc, ew4, rowptr, W3, g3, b3, a, st, scb, xa, stream);
    apply_relu_kernel<64><<<(NPTS * 64 + 255) / 256, 256, 0, stream>>>(xa, scb);

    // Layer 4: cconv(xa; W4) -> P2 (reuse), sigmoid-mix -> out
    run_layer<64, 32>(xa, sc, ew4, rowptr, W4, g4, b4, a, st, scb, P2, stream);
    apply_sigmix_kernel<<<(NPTS * 32 + 255) / 256, 256, 0, stream>>>(P2, scb, x, y, (float*)d_out);
}